// Round 9
// baseline (161.501 us; speedup 1.0000x reference)
//
#include <hip/hip_runtime.h>

// set_transform: out[i,j,q,e] = sum_{h,k} relu((x_j W1)[q,h,:]·(y_j W2)[k,h,:]/8)/128 * (y_i W34)[k,h,e]
// W34[c,h*64+e] = sum_d W3[c,h*64+d] W4[h*64+d,e]   (final @W4 fused into V-proj)
//
// R9: BK 64 -> 128 in the GEMM core (single variable vs R8). Halves the per-K-tile
// vmcnt(0)+lgkmcnt(0) barrier drains (out: 16->8, proj: 8->4) at zero occupancy cost:
// out LDS 32->64KB but grid 512 = 2/CU (64x2=128<=160); proj 24->48KB, grid 768 = 3/CU
// (48x3=144<=160). Staged bytes / MFMA count / K-order identical -> absmax unchanged.
// Numerics: fp16 1-term (R7/R8 validated absmax 1.95e-3 < 7.07e-3).
// Budget (R8 profile): harness fills+restores ~54us + graph gaps ~25us = fixed floor;
// kernels ~66us are the only controllable part (out ~30, proj ~15, attn ~6, prep ~10).

#define MB (1u << 20)

typedef __attribute__((ext_vector_type(8))) _Float16 half8;
typedef __attribute__((ext_vector_type(4))) float f32x4;

enum : size_t {
  OFF_X   = 0,                        // x fp16 [4096][512], 4MB; reused as A[0:4MB) after proj
  OFF_Y   = OFF_X   + 4 * MB,         // y fp16, 4MB; reused as A[4MB:8MB)
  OFF_W1  = OFF_Y   + 4 * MB,         // W1T fp16 [512][512]
  OFF_W2  = OFF_W1  + 512 * 1024,
  OFF_W34 = OFF_W2  + 512 * 1024,     // W34T fp16 [512][512]
  OFF_Q   = OFF_W34 + 512 * 1024,     // [s][h][128][64], 4MB
  OFF_K   = OFF_Q   + 4 * MB,         // 4MB
  OFF_VW  = OFF_K   + 4 * MB,         // [(i*64+e)][h*128+n], 4MB
  WS_NEED = OFF_VW  + 4 * MB,         // 21.5MB
  OFF_A   = OFF_X                     // A fp16 [4096][1024], 8MB, aliases x|y (dead after proj)
};

#define GLOAD_LDS16(g, l)                                                    \
  __builtin_amdgcn_global_load_lds(                                          \
      (const __attribute__((address_space(1))) void*)(g),                    \
      (__attribute__((address_space(3))) void*)(l), 16, 0, 0)

// ---------------------------------------------------------------------------
// prep_xy: x,y f32 -> fp16. 8 floats/thread: 2x float4 load, 1x half8 (16B) store.
// grid 2048 x 256, no LDS, minimal VGPR -> full occupancy, HBM-bound.
// ---------------------------------------------------------------------------
__global__ __launch_bounds__(256) void prep_xy(
    const float* __restrict__ x, const float* __restrict__ y,
    _Float16* xc, _Float16* yc) {
  int idx = blockIdx.x * 256 + threadIdx.x;      // 0..524287
  const float4* src; _Float16* d; int t;
  if (idx < 262144) { src = (const float4*)x; d = xc; t = idx; }
  else              { src = (const float4*)y; d = yc; t = idx - 262144; }
  float4 v0 = src[2 * t], v1 = src[2 * t + 1];
  half8 h = { (_Float16)v0.x, (_Float16)v0.y, (_Float16)v0.z, (_Float16)v0.w,
              (_Float16)v1.x, (_Float16)v1.y, (_Float16)v1.z, (_Float16)v1.w };
  *(half8*)&d[t * 8] = h;
}

// ---------------------------------------------------------------------------
// prep_w: b<128: W1/W2 transpose via padded LDS; b>=128: W34 = per-head W3@W4.
// grid 192 x 256. Pass loops NOT unrolled (R7 lesson: full unroll -> VGPR 208).
// ---------------------------------------------------------------------------
__global__ __launch_bounds__(256) void prep_w(
    const float* __restrict__ W1, const float* __restrict__ W2,
    const float* __restrict__ W3, const float* __restrict__ W4,
    _Float16* w1t, _Float16* w2t, _Float16* w34t) {
  int b = blockIdx.x;
  if (b < 128) {                       // W1/W2 transpose: out[n][c] = W[c][n]
    __shared__ float lt[64][65];
    const float* W = (b < 64) ? W1 : W2;
    _Float16* d   = (b < 64) ? w1t : w2t;
    int t = b & 63;
    int cb = (t >> 3) * 64, nb = (t & 7) * 64;
    for (int it = 0; it < 16; ++it) {
      int idx = it * 256 + threadIdx.x;
      int cl = idx >> 6, nl = idx & 63;
      lt[cl][nl] = W[(cb + cl) * 512 + nb + nl];   // coalesced in n
    }
    __syncthreads();
    for (int it = 0; it < 16; ++it) {
      int idx = it * 256 + threadIdx.x;
      int nl = idx >> 6, cl = idx & 63;
      d[(nb + nl) * 512 + cb + cl] = (_Float16)lt[cl][nl];   // coalesced in c
    }
  } else {                             // W34T[(h*64+e)][c] = sum_d W3[c][h*64+d]*W4[h*64+d][e]
    __shared__ float l3[64][65];       // [c_local][d]
    __shared__ float l4[64][65];       // [d][e]
    int t = b - 128;
    int h = t >> 3, cb = (t & 7) * 64;
    for (int it = 0; it < 16; ++it) {
      int idx = it * 256 + threadIdx.x;
      int r = idx >> 6, cidx = idx & 63;
      l3[r][cidx] = W3[(cb + r) * 512 + h * 64 + cidx];
      l4[r][cidx] = W4[(h * 64 + r) * 64 + cidx];
    }
    __syncthreads();
    for (int pass = 0; pass < 16; ++pass) {       // not unrolled: keep VGPR low
      int cl = threadIdx.x & 63;
      int el = pass * 4 + (threadIdx.x >> 6);
      float acc = 0.f;
#pragma unroll
      for (int d = 0; d < 64; ++d)
        acc += l3[cl][d] * l4[d][el];
      w34t[(h * 64 + el) * 512 + cb + cl] = (_Float16)acc;
    }
  }
}

// ---------------------------------------------------------------------------
// GEMM core: BM x 128 tile, 4 waves (2x2), K in BK chunks, single-buffer,
// stage -> barrier -> compute -> barrier (R3-proven). Linear LDS rows
// (BK fp16 = 2*BK bytes/row). A,B row-major, k contiguous (NT form).
// ---------------------------------------------------------------------------
template <int BM, int MF, int NF, int BK, int KTILES, typename EPI>
__device__ __forceinline__ void gemm_core(
    const _Float16* __restrict__ A, const _Float16* __restrict__ B,
    int row_stride_bytes, EPI&& epi) {
  constexpr int BN = 2 * NF * 16;       // 128 (WN=2)
  constexpr int ROWB = BK * 2;          // bytes per LDS row
  constexpr int ABYTES = BM * ROWB;
  constexpr int BBYTES = BN * ROWB;
  constexpr int TOTAL = ABYTES + BBYTES;
  constexpr int ITERS = TOTAL / 4096;   // 16B x 256 threads per iter
  static_assert(TOTAL % 4096 == 0 && ABYTES % 4096 == 0, "");
  __shared__ alignas(16) char smem[TOTAL];
  _Float16* sA = (_Float16*)smem;
  _Float16* sB = (_Float16*)(smem + ABYTES);

  const int tid  = threadIdx.x;
  const int lane = tid & 63;
  const int wid  = tid >> 6;
  const int wm   = wid >> 1, wn = wid & 1;
  const int lr   = lane & 15;
  const int lk   = (lane >> 4) * 8;

  f32x4 acc[MF][NF];
#pragma unroll
  for (int i = 0; i < MF; ++i)
#pragma unroll
    for (int j = 0; j < NF; ++j) acc[i][j] = (f32x4){0.f, 0.f, 0.f, 0.f};

  for (int kc = 0; kc < KTILES; ++kc) {
    if (kc) __syncthreads();
#pragma unroll
    for (int i = 0; i < ITERS; ++i) {
      int o = i * 4096 + wid * 1024 + lane * 16;   // flat byte offset
      const char* g; int lo_;
      if (o < ABYTES) { g = (const char*)A; lo_ = o; }
      else            { g = (const char*)B; lo_ = o - ABYTES; }
      int row = lo_ / ROWB, cb = lo_ % ROWB;
      GLOAD_LDS16(g + (size_t)row * row_stride_bytes + kc * ROWB + cb,
                  smem + i * 4096 + wid * 1024);
    }
    __syncthreads();
#pragma unroll
    for (int ks = 0; ks < BK / 32; ++ks) {
      half8 a[MF], bfr[NF];
#pragma unroll
      for (int f = 0; f < MF; ++f)
        a[f] = *(const half8*)&sA[(wm * (MF * 16) + f * 16 + lr) * BK + ks * 32 + lk];
#pragma unroll
      for (int f = 0; f < NF; ++f)
        bfr[f] = *(const half8*)&sB[(wn * (NF * 16) + f * 16 + lr) * BK + ks * 32 + lk];
#pragma unroll
      for (int fm = 0; fm < MF; ++fm)
#pragma unroll
        for (int fn = 0; fn < NF; ++fn)
          acc[fm][fn] = __builtin_amdgcn_mfma_f32_16x16x32_f16(a[fm], bfr[fn], acc[fm][fn], 0, 0, 0);
    }
  }
  // C/D layout (m89-verified): col = lane&15, row = (lane>>4)*4 + reg
#pragma unroll
  for (int fm = 0; fm < MF; ++fm)
#pragma unroll
    for (int fn = 0; fn < NF; ++fn)
#pragma unroll
      for (int r = 0; r < 4; ++r) {
        int ml = wm * (MF * 16) + fm * 16 + (lane >> 4) * 4 + r;
        int nl = wn * (NF * 16) + fn * 16 + lr;
        epi(ml, nl, acc[fm][fn][r]);
      }
}

// ---------------------------------------------------------------------------
// proj: z=0 Q=x@W1T, z=1 K=y@W2T, z=2 VW=y@W34T.  M=4096,N=512,K=512.
// 64x128 tiles, BK=128 x 4: grid (64, 4, 3) x 256 = 768 blocks (3/CU), LDS 48KB
// ---------------------------------------------------------------------------
__global__ __launch_bounds__(256) void proj_gemm(
    const _Float16* __restrict__ xc, const _Float16* __restrict__ yc,
    const _Float16* __restrict__ w1t, const _Float16* __restrict__ w2t,
    const _Float16* __restrict__ w34t,
    _Float16* q, _Float16* k, _Float16* vw) {
  const int mt = blockIdx.x, nt = blockIdx.y, z = blockIdx.z;
  const _Float16 *A, *B;
  if (z == 0)      { A = xc; B = w1t; }
  else if (z == 1) { A = yc; B = w2t; }
  else             { A = yc; B = w34t; }
  A += (size_t)mt * 64 * 512;
  B += (size_t)nt * 128 * 512;

  gemm_core<64, 2, 4, 128, 4>(A, B, 1024, [&](int ml, int nl, float v) {
    int row = mt * 64 + ml;           // (s, item)
    int col = nt * 128 + nl;          // (h, d|e)
    int s = row >> 7, n = row & 127;
    int h = col >> 6, d = col & 63;
    _Float16 hv = (_Float16)v;
    if (z == 0)      q[((s * 8 + h) * 128 + n) * 64 + d] = hv;
    else if (z == 1) k[((s * 8 + h) * 128 + n) * 64 + d] = hv;
    else             vw[(s * 64 + d) * 1024 + h * 128 + n] = hv;
  });
}

// ---------------------------------------------------------------------------
// attn: per (s,h): relu(Q K^T / 8)/128 -> A[(s*128+q)][(h*128+k)].  M=N=128,K=64.
// 64x128 tiles, BK=64 x 1: grid (64, 8) x 256 = 512 blocks, LDS 24KB
// ---------------------------------------------------------------------------
__global__ __launch_bounds__(256) void attn_gemm(
    const _Float16* __restrict__ q, const _Float16* __restrict__ k,
    _Float16* a) {
  const int s = blockIdx.x >> 1, msub = blockIdx.x & 1, h = blockIdx.y;
  const size_t offq = (size_t)(s * 8 + h) * 128 * 64 + (size_t)msub * 64 * 64;
  const size_t offk = (size_t)(s * 8 + h) * 128 * 64;
  gemm_core<64, 2, 4, 64, 1>(q + offq, k + offk, 128, [&](int ml, int nl, float v) {
    v = fmaxf(v * 0.125f, 0.f) * (1.0f / 128.0f);
    int qq = msub * 64 + ml;
    a[(s * 128 + qq) * 1024 + h * 128 + nl] = (_Float16)v;
  });
}

// ---------------------------------------------------------------------------
// out: [4096,1024] @ [2048,1024]^T -> out[i,j,q,e].  M=4096,N=2048,K=1024.
// 128x128 tiles, BK=128 x 8: grid (32, 16) x 256 = 512 blocks (2/CU), LDS 64KB
// ---------------------------------------------------------------------------
__global__ __launch_bounds__(256) void out_gemm(
    const _Float16* __restrict__ a, const _Float16* __restrict__ vw,
    float* __restrict__ out) {
  const int mt = blockIdx.x, nt = blockIdx.y;
  gemm_core<128, 4, 4, 128, 8>(a + (size_t)mt * 128 * 1024,
                               vw + (size_t)nt * 128 * 1024, 2048,
                               [&](int ml, int nl, float v) {
                                 int row = mt * 128 + ml;    // (j, q)
                                 int col = nt * 128 + nl;    // (i, e)
                                 int i = col >> 6, e = col & 63;
                                 int j = row >> 7, qq = row & 127;
                                 out[(size_t)(((i * 32 + j) * 128 + qq)) * 64 + e] = v;
                               });
}

// ---------------------------------------------------------------------------
extern "C" void kernel_launch(void* const* d_in, const int* in_sizes, int n_in,
                              void* d_out, int out_size, void* d_ws, size_t ws_size,
                              hipStream_t stream) {
  const float* x  = (const float*)d_in[0];
  const float* y  = (const float*)d_in[1];
  const float* W1 = (const float*)d_in[2];
  const float* W2 = (const float*)d_in[3];
  const float* W3 = (const float*)d_in[4];
  const float* W4 = (const float*)d_in[5];
  float* out = (float*)d_out;
  char* ws = (char*)d_ws;

  _Float16* xc   = (_Float16*)(ws + OFF_X);
  _Float16* yc   = (_Float16*)(ws + OFF_Y);
  _Float16* w1t  = (_Float16*)(ws + OFF_W1);
  _Float16* w2t  = (_Float16*)(ws + OFF_W2);
  _Float16* w34t = (_Float16*)(ws + OFF_W34);
  _Float16* q    = (_Float16*)(ws + OFF_Q);
  _Float16* k    = (_Float16*)(ws + OFF_K);
  _Float16* vw   = (_Float16*)(ws + OFF_VW);
  _Float16* a    = (_Float16*)(ws + OFF_A);   // aliases xc|yc (dead after proj)

  prep_w<<<192, 256, 0, stream>>>(W1, W2, W3, W4, w1t, w2t, w34t);
  prep_xy<<<2048, 256, 0, stream>>>(x, y, xc, yc);
  proj_gemm<<<dim3(64, 4, 3), 256, 0, stream>>>(xc, yc, w1t, w2t, w34t, q, k, vw);
  attn_gemm<<<dim3(64, 8), 256, 0, stream>>>(q, k, a);
  out_gemm<<<dim3(32, 16), 256, 0, stream>>>(a, vw, out);
}

// Round 11
// 147.003 us; speedup vs baseline: 1.0986x; 1.0986x over previous
//
#include <hip/hip_runtime.h>

// set_transform: out[i,j,q,e] = sum_{h,k} relu((x_j W1)[q,h,:]·(y_j W2)[k,h,:]/8)/128 * (y_i W34)[k,h,e]
// W34[c,h*64+e] = sum_d W3[c,h*64+d] W4[h*64+d,e]   (final @W4 fused into V-proj)
//
// R10/R11: revert BK to 64 (R9's BK=128 regressed +16us — m132 pattern: longer stage
// bursts + bigger LDS hurt inter-block overlap). Single new variable: out_gemm
// tile 128x128 -> 64x128, grid (64,16)=1024 = 4 blocks/CU (was 512 = 2/CU,
// GRID-limited; m97's 874TF reference ran this structure at 4/CU). LDS 24KB.
// Staging 268->384MB L2 (~11us aggregate, under budget); K-order identical.
// Numerics: fp16 1-term (validated absmax 1.95e-3 < 7.07e-3, R7/R8/R9).

#define MB (1u << 20)

typedef __attribute__((ext_vector_type(8))) _Float16 half8;
typedef __attribute__((ext_vector_type(4))) float f32x4;

enum : size_t {
  OFF_X   = 0,                        // x fp16 [4096][512], 4MB; reused as A[0:4MB) after proj
  OFF_Y   = OFF_X   + 4 * MB,         // y fp16, 4MB; reused as A[4MB:8MB)
  OFF_W1  = OFF_Y   + 4 * MB,         // W1T fp16 [512][512]
  OFF_W2  = OFF_W1  + 512 * 1024,
  OFF_W34 = OFF_W2  + 512 * 1024,     // W34T fp16 [512][512]
  OFF_Q   = OFF_W34 + 512 * 1024,     // [s][h][128][64], 4MB
  OFF_K   = OFF_Q   + 4 * MB,         // 4MB
  OFF_VW  = OFF_K   + 4 * MB,         // [(i*64+e)][h*128+n], 4MB
  WS_NEED = OFF_VW  + 4 * MB,         // 21.5MB
  OFF_A   = OFF_X                     // A fp16 [4096][1024], 8MB, aliases x|y (dead after proj)
};

#define GLOAD_LDS16(g, l)                                                    \
  __builtin_amdgcn_global_load_lds(                                          \
      (const __attribute__((address_space(1))) void*)(g),                    \
      (__attribute__((address_space(3))) void*)(l), 16, 0, 0)

// ---------------------------------------------------------------------------
// prep_xy: x,y f32 -> fp16. 8 floats/thread: 2x float4 load, 1x half8 (16B) store.
// grid 2048 x 256, no LDS, minimal VGPR -> full occupancy, HBM-bound.
// ---------------------------------------------------------------------------
__global__ __launch_bounds__(256) void prep_xy(
    const float* __restrict__ x, const float* __restrict__ y,
    _Float16* xc, _Float16* yc) {
  int idx = blockIdx.x * 256 + threadIdx.x;      // 0..524287
  const float4* src; _Float16* d; int t;
  if (idx < 262144) { src = (const float4*)x; d = xc; t = idx; }
  else              { src = (const float4*)y; d = yc; t = idx - 262144; }
  float4 v0 = src[2 * t], v1 = src[2 * t + 1];
  half8 h = { (_Float16)v0.x, (_Float16)v0.y, (_Float16)v0.z, (_Float16)v0.w,
              (_Float16)v1.x, (_Float16)v1.y, (_Float16)v1.z, (_Float16)v1.w };
  *(half8*)&d[t * 8] = h;
}

// ---------------------------------------------------------------------------
// prep_w: b<128: W1/W2 transpose via padded LDS; b>=128: W34 = per-head W3@W4.
// grid 192 x 256. Pass loops NOT unrolled (R7 lesson: full unroll -> VGPR 208).
// ---------------------------------------------------------------------------
__global__ __launch_bounds__(256) void prep_w(
    const float* __restrict__ W1, const float* __restrict__ W2,
    const float* __restrict__ W3, const float* __restrict__ W4,
    _Float16* w1t, _Float16* w2t, _Float16* w34t) {
  int b = blockIdx.x;
  if (b < 128) {                       // W1/W2 transpose: out[n][c] = W[c][n]
    __shared__ float lt[64][65];
    const float* W = (b < 64) ? W1 : W2;
    _Float16* d   = (b < 64) ? w1t : w2t;
    int t = b & 63;
    int cb = (t >> 3) * 64, nb = (t & 7) * 64;
    for (int it = 0; it < 16; ++it) {
      int idx = it * 256 + threadIdx.x;
      int cl = idx >> 6, nl = idx & 63;
      lt[cl][nl] = W[(cb + cl) * 512 + nb + nl];   // coalesced in n
    }
    __syncthreads();
    for (int it = 0; it < 16; ++it) {
      int idx = it * 256 + threadIdx.x;
      int nl = idx >> 6, cl = idx & 63;
      d[(nb + nl) * 512 + cb + cl] = (_Float16)lt[cl][nl];   // coalesced in c
    }
  } else {                             // W34T[(h*64+e)][c] = sum_d W3[c][h*64+d]*W4[h*64+d][e]
    __shared__ float l3[64][65];       // [c_local][d]
    __shared__ float l4[64][65];       // [d][e]
    int t = b - 128;
    int h = t >> 3, cb = (t & 7) * 64;
    for (int it = 0; it < 16; ++it) {
      int idx = it * 256 + threadIdx.x;
      int r = idx >> 6, cidx = idx & 63;
      l3[r][cidx] = W3[(cb + r) * 512 + h * 64 + cidx];
      l4[r][cidx] = W4[(h * 64 + r) * 64 + cidx];
    }
    __syncthreads();
    for (int pass = 0; pass < 16; ++pass) {       // not unrolled: keep VGPR low
      int cl = threadIdx.x & 63;
      int el = pass * 4 + (threadIdx.x >> 6);
      float acc = 0.f;
#pragma unroll
      for (int d = 0; d < 64; ++d)
        acc += l3[cl][d] * l4[d][el];
      w34t[(h * 64 + el) * 512 + cb + cl] = (_Float16)acc;
    }
  }
}

// ---------------------------------------------------------------------------
// GEMM core (R8-proven, BK=64): BM x 128 tile, 4 waves (2x2), single-buffer,
// stage -> barrier -> compute -> barrier. Linear LDS rows (64 fp16 = 128B).
// A,B row-major, k contiguous (NT form).
// ---------------------------------------------------------------------------
template <int BM, int MF, int NF, int KTILES, typename EPI>
__device__ __forceinline__ void gemm_core(
    const _Float16* __restrict__ A, const _Float16* __restrict__ B,
    int row_stride_bytes, EPI&& epi) {
  constexpr int BN = 2 * NF * 16;       // 128 (WN=2)
  constexpr int ABYTES = BM * 128;      // BM rows x 64 k x 2B
  constexpr int BBYTES = BN * 128;
  constexpr int TOTAL = ABYTES + BBYTES;
  constexpr int ITERS = TOTAL / 4096;   // 16B x 256 threads per iter
  static_assert(TOTAL % 4096 == 0 && ABYTES % 4096 == 0, "");
  __shared__ alignas(16) char smem[TOTAL];
  _Float16* sA = (_Float16*)smem;
  _Float16* sB = (_Float16*)(smem + ABYTES);

  const int tid  = threadIdx.x;
  const int lane = tid & 63;
  const int wid  = tid >> 6;
  const int wm   = wid >> 1, wn = wid & 1;
  const int lr   = lane & 15;
  const int lk   = (lane >> 4) * 8;

  f32x4 acc[MF][NF];
#pragma unroll
  for (int i = 0; i < MF; ++i)
#pragma unroll
    for (int j = 0; j < NF; ++j) acc[i][j] = (f32x4){0.f, 0.f, 0.f, 0.f};

  for (int kc = 0; kc < KTILES; ++kc) {
    if (kc) __syncthreads();
#pragma unroll
    for (int i = 0; i < ITERS; ++i) {
      int o = i * 4096 + wid * 1024 + lane * 16;   // flat byte offset
      const char* g; int lo_;
      if (o < ABYTES) { g = (const char*)A; lo_ = o; }
      else            { g = (const char*)B; lo_ = o - ABYTES; }
      GLOAD_LDS16(g + (size_t)(lo_ >> 7) * row_stride_bytes + kc * 128 + (lo_ & 127),
                  smem + i * 4096 + wid * 1024);
    }
    __syncthreads();
#pragma unroll
    for (int ks = 0; ks < 2; ++ks) {
      half8 a[MF], bfr[NF];
#pragma unroll
      for (int f = 0; f < MF; ++f)
        a[f] = *(const half8*)&sA[(wm * (MF * 16) + f * 16 + lr) * 64 + ks * 32 + lk];
#pragma unroll
      for (int f = 0; f < NF; ++f)
        bfr[f] = *(const half8*)&sB[(wn * (NF * 16) + f * 16 + lr) * 64 + ks * 32 + lk];
#pragma unroll
      for (int fm = 0; fm < MF; ++fm)
#pragma unroll
        for (int fn = 0; fn < NF; ++fn)
          acc[fm][fn] = __builtin_amdgcn_mfma_f32_16x16x32_f16(a[fm], bfr[fn], acc[fm][fn], 0, 0, 0);
    }
  }
  // C/D layout (m89-verified): col = lane&15, row = (lane>>4)*4 + reg
#pragma unroll
  for (int fm = 0; fm < MF; ++fm)
#pragma unroll
    for (int fn = 0; fn < NF; ++fn)
#pragma unroll
      for (int r = 0; r < 4; ++r) {
        int ml = wm * (MF * 16) + fm * 16 + (lane >> 4) * 4 + r;
        int nl = wn * (NF * 16) + fn * 16 + lr;
        epi(ml, nl, acc[fm][fn][r]);
      }
}

// ---------------------------------------------------------------------------
// proj: z=0 Q=x@W1T, z=1 K=y@W2T, z=2 VW=y@W34T.  M=4096,N=512,K=512.
// 64x128 tiles, BK=64 x 8: grid (64, 4, 3) x 256 = 768 blocks (3/CU), LDS 24KB
// ---------------------------------------------------------------------------
__global__ __launch_bounds__(256) void proj_gemm(
    const _Float16* __restrict__ xc, const _Float16* __restrict__ yc,
    const _Float16* __restrict__ w1t, const _Float16* __restrict__ w2t,
    const _Float16* __restrict__ w34t,
    _Float16* q, _Float16* k, _Float16* vw) {
  const int mt = blockIdx.x, nt = blockIdx.y, z = blockIdx.z;
  const _Float16 *A, *B;
  if (z == 0)      { A = xc; B = w1t; }
  else if (z == 1) { A = yc; B = w2t; }
  else             { A = yc; B = w34t; }
  A += (size_t)mt * 64 * 512;
  B += (size_t)nt * 128 * 512;

  gemm_core<64, 2, 4, 8>(A, B, 1024, [&](int ml, int nl, float v) {
    int row = mt * 64 + ml;           // (s, item)
    int col = nt * 128 + nl;          // (h, d|e)
    int s = row >> 7, n = row & 127;
    int h = col >> 6, d = col & 63;
    _Float16 hv = (_Float16)v;
    if (z == 0)      q[((s * 8 + h) * 128 + n) * 64 + d] = hv;
    else if (z == 1) k[((s * 8 + h) * 128 + n) * 64 + d] = hv;
    else             vw[(s * 64 + d) * 1024 + h * 128 + n] = hv;
  });
}

// ---------------------------------------------------------------------------
// attn: per (s,h): relu(Q K^T / 8)/128 -> A[(s*128+q)][(h*128+k)].  M=N=128,K=64.
// 64x128 tiles, BK=64 x 1: grid (64, 8) x 256 = 512 blocks, LDS 24KB
// ---------------------------------------------------------------------------
__global__ __launch_bounds__(256) void attn_gemm(
    const _Float16* __restrict__ q, const _Float16* __restrict__ k,
    _Float16* a) {
  const int s = blockIdx.x >> 1, msub = blockIdx.x & 1, h = blockIdx.y;
  const size_t offq = (size_t)(s * 8 + h) * 128 * 64 + (size_t)msub * 64 * 64;
  const size_t offk = (size_t)(s * 8 + h) * 128 * 64;
  gemm_core<64, 2, 4, 1>(q + offq, k + offk, 128, [&](int ml, int nl, float v) {
    v = fmaxf(v * 0.125f, 0.f) * (1.0f / 128.0f);
    int qq = msub * 64 + ml;
    a[(s * 128 + qq) * 1024 + h * 128 + nl] = (_Float16)v;
  });
}

// ---------------------------------------------------------------------------
// out: [4096,1024] @ [2048,1024]^T -> out[i,j,q,e].  M=4096,N=2048,K=1024.
// 64x128 tiles, BK=64 x 16: grid (64, 16) x 256 = 1024 blocks (4/CU), LDS 24KB
// (was 128x128 / 512 blocks = 2/CU grid-limited; m97 structure wants 4/CU)
// ---------------------------------------------------------------------------
__global__ __launch_bounds__(256) void out_gemm(
    const _Float16* __restrict__ a, const _Float16* __restrict__ vw,
    float* __restrict__ out) {
  const int mt = blockIdx.x, nt = blockIdx.y;
  gemm_core<64, 2, 4, 16>(a + (size_t)mt * 64 * 1024,
                          vw + (size_t)nt * 128 * 1024, 2048,
                          [&](int ml, int nl, float v) {
                            int row = mt * 64 + ml;     // (j, q)
                            int col = nt * 128 + nl;    // (i, e)
                            int i = col >> 6, e = col & 63;
                            int j = row >> 7, qq = row & 127;
                            out[(size_t)(((i * 32 + j) * 128 + qq)) * 64 + e] = v;
                          });
}

// ---------------------------------------------------------------------------
extern "C" void kernel_launch(void* const* d_in, const int* in_sizes, int n_in,
                              void* d_out, int out_size, void* d_ws, size_t ws_size,
                              hipStream_t stream) {
  const float* x  = (const float*)d_in[0];
  const float* y  = (const float*)d_in[1];
  const float* W1 = (const float*)d_in[2];
  const float* W2 = (const float*)d_in[3];
  const float* W3 = (const float*)d_in[4];
  const float* W4 = (const float*)d_in[5];
  float* out = (float*)d_out;
  char* ws = (char*)d_ws;

  _Float16* xc   = (_Float16*)(ws + OFF_X);
  _Float16* yc   = (_Float16*)(ws + OFF_Y);
  _Float16* w1t  = (_Float16*)(ws + OFF_W1);
  _Float16* w2t  = (_Float16*)(ws + OFF_W2);
  _Float16* w34t = (_Float16*)(ws + OFF_W34);
  _Float16* q    = (_Float16*)(ws + OFF_Q);
  _Float16* k    = (_Float16*)(ws + OFF_K);
  _Float16* vw   = (_Float16*)(ws + OFF_VW);
  _Float16* a    = (_Float16*)(ws + OFF_A);   // aliases xc|yc (dead after proj)

  prep_w<<<192, 256, 0, stream>>>(W1, W2, W3, W4, w1t, w2t, w34t);
  prep_xy<<<2048, 256, 0, stream>>>(x, y, xc, yc);
  proj_gemm<<<dim3(64, 4, 3), 256, 0, stream>>>(xc, yc, w1t, w2t, w34t, q, k, vw);
  attn_gemm<<<dim3(64, 8), 256, 0, stream>>>(q, k, a);
  out_gemm<<<dim3(64, 16), 256, 0, stream>>>(a, vw, out);
}